// Round 11
// baseline (406.959 us; speedup 1.0000x reference)
//
#include <hip/hip_runtime.h>
#include <math.h>

#define HW 65536

typedef float f32x4 __attribute__((ext_vector_type(4)));
typedef short bf16x8 __attribute__((ext_vector_type(8)));
typedef short bf16x4 __attribute__((ext_vector_type(4)));

// ---- ws layout (byte offsets) ----
static constexpr size_t OFF_A0     = 0;
static constexpr size_t OFF_SP     = 50331648;
static constexpr size_t OFF_VOUTT  = 100663296;
static constexpr size_t OFF_XQK    = 150994944;
static constexpr size_t OFF_VPL    = 251658240;
static constexpr size_t OFF_PT     = 301989888;  // 1,048,576 B
static constexpr size_t OFF_NORMP  = 303038464;  // 16,384 B (atomic partials)
static constexpr size_t OFF_WQ     = 303054848;  // 221,184 B
static constexpr size_t OFF_WP     = 303276032;  // 73,728 B
static constexpr size_t OFF_NORMS  = 303349760;  // 16,384 B  (end 303,366,144)

__device__ inline float b2f(unsigned short u) { union { unsigned u; float f; } v; v.u = ((unsigned)u) << 16; return v.f; }
__device__ inline unsigned short f2b(float f) {
    union { float f; unsigned u; } v; v.f = f;
    return (unsigned short)((v.u + 0x7fffu + ((v.u >> 16) & 1u)) >> 16);
}

// ---------------- convert weights to bf16
__global__ __launch_bounds__(256) void conv_w(const float* __restrict__ wq, const float* __restrict__ wp,
                                              unsigned short* __restrict__ wqb, unsigned short* __restrict__ wpb)
{
    int t = blockIdx.x * 256 + threadIdx.x;
    int stride = gridDim.x * 256;
    for (int i = t; i < 576 * 192; i += stride) wqb[i] = f2b(wq[i]);
    for (int i = t; i < 192 * 192; i += stride) wpb[i] = f2b(wp[i]);
}

// ---------------- x fp32 planar [b][192][HW] -> xb bf16 pixel-major [b*HW][192]
__global__ __launch_bounds__(256) void conv_x(const float* __restrict__ x, unsigned short* __restrict__ xb)
{
    __shared__ unsigned short T[64 * 200];   // [px 64][c 192 pad 200]
    int tid = threadIdx.x;
    int b = blockIdx.y;
    long p0 = (long)blockIdx.x * 64;
#pragma unroll
    for (int it = 0; it < 12; ++it) {
        int c = it * 16 + (tid >> 4);
        int px = (tid & 15) * 4;
        float4 v = *(const float4*)(x + ((long)b * 192 + c) * HW + p0 + px);
        T[(px + 0) * 200 + c] = f2b(v.x);
        T[(px + 1) * 200 + c] = f2b(v.y);
        T[(px + 2) * 200 + c] = f2b(v.z);
        T[(px + 3) * 200 + c] = f2b(v.w);
    }
    __syncthreads();
    int px = tid >> 2, q = tid & 3;
    unsigned short* ob = xb + ((long)b * HW + p0 + px) * 192 + q * 48;
#pragma unroll
    for (int e = 0; e < 6; ++e)
        *(bf16x8*)(ob + e * 8) = *(const bf16x8*)&T[px * 200 + q * 48 + e * 8];
}

// ---------------- MFMA GEMM v2 (proven fastest): 128-px tile, coalesced LDS staging,
// b128 fragment gather, loop over M-tiles.
__global__ __launch_bounds__(256) void gemm_pm2(const unsigned short* __restrict__ Aw,
                                                const unsigned short* __restrict__ Bp,
                                                unsigned short* __restrict__ outb,
                                                float* __restrict__ outf, int Mtiles)
{
    __shared__ unsigned short Bs[128 * 200];
    int tid = threadIdx.x;
    int w = tid >> 6, lane = tid & 63, lg = lane >> 4, li = lane & 15;
    int wm = w >> 1, wn = w & 1;
    long pflat = (long)blockIdx.x * 128;

#pragma unroll
    for (int it = 0; it < 12; ++it) {
        int f = it * 256 + tid;
        int row = f / 24, cs = (f % 24) * 8;
        *(bf16x8*)&Bs[row * 200 + cs] = *(const bf16x8*)(Bp + (pflat + row) * 192 + cs);
    }
    __syncthreads();

    bf16x8 Bf[4][6];
#pragma unroll
    for (int fb = 0; fb < 4; ++fb)
#pragma unroll
        for (int ks = 0; ks < 6; ++ks)
            Bf[fb][ks] = *(const bf16x8*)&Bs[(wn * 64 + fb * 16 + li) * 200 + ks * 32 + lg * 8];

    const int b = (int)(blockIdx.x >> 9);
    const int pxl = ((int)blockIdx.x & 511) * 128 + wn * 64;
    const int Mtot = Mtiles * 64;

    for (int mt = 0; mt < Mtiles; ++mt) {
        int oc0 = mt * 64;
        const unsigned short* ab = Aw + (long)(oc0 + wm * 32 + li) * 192 + lg * 8;
        f32x4 acc[2][4];
#pragma unroll
        for (int i = 0; i < 2; ++i)
#pragma unroll
            for (int j = 0; j < 4; ++j) acc[i][j] = (f32x4){0.f, 0.f, 0.f, 0.f};
#pragma unroll
        for (int ks = 0; ks < 6; ++ks) {
            bf16x8 a0 = *(const bf16x8*)(ab + ks * 32);
            bf16x8 a1 = *(const bf16x8*)(ab + 16 * 192 + ks * 32);
#pragma unroll
            for (int fb = 0; fb < 4; ++fb) {
                acc[0][fb] = __builtin_amdgcn_mfma_f32_16x16x32_bf16(a0, Bf[fb][ks], acc[0][fb], 0, 0, 0);
                acc[1][fb] = __builtin_amdgcn_mfma_f32_16x16x32_bf16(a1, Bf[fb][ks], acc[1][fb], 0, 0, 0);
            }
        }
#pragma unroll
        for (int fa = 0; fa < 2; ++fa) {
            int m = oc0 + wm * 32 + fa * 16 + lg * 4;
#pragma unroll
            for (int fb = 0; fb < 4; ++fb) {
                int px = pxl + fb * 16 + li;
                long base = ((long)b * Mtot + m) * HW + px;
#pragma unroll
                for (int ii = 0; ii < 4; ++ii) {
                    if (outf) outf[base + (long)ii * HW] = acc[fa][fb][ii];
                    else      outb[base + (long)ii * HW] = f2b(acc[fa][fb][ii]);
                }
            }
        }
    }
}

// ---------------- depthwise 3x3 SAME v3: as v2 + fused q/k column sum-of-squares
// (LDS reduce + atomicAdd into normp[16][256]); norms_k kernel deleted.
__global__ __launch_bounds__(256) void dwconv2(const unsigned short* __restrict__ in,
                                               const float* __restrict__ wdw,
                                               unsigned short* __restrict__ qkT,
                                               unsigned short* __restrict__ vpl,
                                               float* __restrict__ normp)
{
    __shared__ unsigned short Ls[34 * 272];
    int tid = threadIdx.x;
    int zp = blockIdx.y;
    int b = zp / 576, ch3 = zp % 576;
    int y0 = blockIdx.x * 32;
    const unsigned short* ip = in + (long)zp * HW;
    float w9[9];
#pragma unroll
    for (int t = 0; t < 9; ++t) w9[t] = wdw[ch3 * 9 + t];

    const bf16x8 z8 = (bf16x8){0, 0, 0, 0, 0, 0, 0, 0};
    if (tid < 34)               *(bf16x8*)&Ls[tid * 272] = z8;
    else if (tid < 68)          *(bf16x8*)&Ls[(tid - 34) * 272 + 264] = z8;
#pragma unroll
    for (int it = 0; it < 5; ++it) {
        int task = it * 256 + tid;
        if (task < 1088) {
            int r = task >> 5, seg = task & 31;
            int gy = y0 - 1 + r;
            bf16x8 v = z8;
            if (gy >= 0 && gy < 256) v = *(const bf16x8*)(ip + gy * 256 + seg * 8);
            *(bf16x8*)&Ls[r * 272 + 8 + seg * 8] = v;
        }
    }
    __syncthreads();

    int xg = tid & 63, yg = tid >> 6;
    int x0 = xg * 4;
    float acc[8][4];
#pragma unroll
    for (int yy = 0; yy < 8; ++yy)
#pragma unroll
        for (int xi = 0; xi < 4; ++xi) acc[yy][xi] = 0.f;

#pragma unroll
    for (int rr = 0; rr < 10; ++rr) {
        const unsigned short* lp = &Ls[(yg * 8 + rr) * 272 + 8 + x0];
        bf16x4 A  = *(const bf16x4*)(lp - 4);
        bf16x4 Bv = *(const bf16x4*)(lp);
        bf16x4 Cv = *(const bf16x4*)(lp + 4);
        float f[6] = { b2f((unsigned short)A[3]),  b2f((unsigned short)Bv[0]),
                       b2f((unsigned short)Bv[1]), b2f((unsigned short)Bv[2]),
                       b2f((unsigned short)Bv[3]), b2f((unsigned short)Cv[0]) };
#pragma unroll
        for (int dy = 0; dy < 3; ++dy) {
            int yy = rr - dy;
            if (yy >= 0 && yy < 8) {
#pragma unroll
                for (int dx = 0; dx < 3; ++dx)
#pragma unroll
                    for (int xi = 0; xi < 4; ++xi)
                        acc[yy][xi] = fmaf(w9[dy * 3 + dx], f[dx + xi], acc[yy][xi]);
            }
        }
    }

    if (ch3 < 384) {
        int isk = ch3 >= 192 ? 1 : 0;
        int chq = ch3 - isk * 192;
        int hh = chq / 48, cc = chq % 48;
        int z2 = b * 8 + isk * 4 + hh;
        long zbase = (long)z2 * 3145728L + (long)cc * 256 + y0 + yg * 8;
#pragma unroll
        for (int xi = 0; xi < 4; ++xi) {
            bf16x8 pv;
#pragma unroll
            for (int yy = 0; yy < 8; ++yy) pv[yy] = (short)f2b(acc[yy][xi]);
            *(bf16x8*)(qkT + zbase + (long)(x0 + xi) * 12288) = pv;
        }
        // fused column sum-of-squares -> normp[z2][x] (Ls is dead; reuse as fp32 scratch)
        float s[4];
#pragma unroll
        for (int xi = 0; xi < 4; ++xi) {
            float t = 0.f;
#pragma unroll
            for (int yy = 0; yy < 8; ++yy) t = fmaf(acc[yy][xi], acc[yy][xi], t);
            s[xi] = t;
        }
        __syncthreads();
        float* colsq = (float*)Ls;   // [4][256] = 4 KB
#pragma unroll
        for (int xi = 0; xi < 4; ++xi) colsq[yg * 256 + x0 + xi] = s[xi];
        __syncthreads();
        if (yg == 0) {
#pragma unroll
            for (int xi = 0; xi < 4; ++xi) {
                float t = colsq[x0 + xi] + colsq[256 + x0 + xi] +
                          colsq[512 + x0 + xi] + colsq[768 + x0 + xi];
                atomicAdd(&normp[z2 * 256 + x0 + xi], t);
            }
        }
    } else {
        unsigned short* ob = vpl + (long)(b * 192 + ch3 - 384) * HW + (long)(y0 + yg * 8) * 256 + x0;
#pragma unroll
        for (int yy = 0; yy < 8; ++yy) {
            bf16x4 pv;
#pragma unroll
            for (int xi = 0; xi < 4; ++xi) pv[xi] = (short)f2b(acc[yy][xi]);
            *(bf16x4*)(ob + yy * 256) = pv;
        }
    }
}

// ---------------- finalize norms: 1/max(sqrt(sumsq),eps)
__global__ __launch_bounds__(256) void norms_fin(const float* __restrict__ normp, float* __restrict__ norms)
{
    int x = threadIdx.x, g = blockIdx.x;
    norms[g * 256 + x] = 1.0f / fmaxf(sqrtf(normp[g * 256 + x]), 1e-12f);
}

// ---------------- generic bf16 transpose (64x64 tiles), mode 1: vout planar -> voutT pixel-major
__global__ __launch_bounds__(256) void transpose_bf16(const unsigned short* __restrict__ src,
                                                      unsigned short* __restrict__ dst, int mode)
{
    __shared__ unsigned short T[64][72];
    int tid = threadIdx.x;
    int z = blockIdx.z;
    long so, dofs; int R, C;
    if (mode == 0) {
        int b = z >> 3, isk = (z >> 2) & 1, h = z & 3;
        so = ((long)(b * 576 + isk * 192 + h * 48)) * HW;
        dofs = (long)z * 12288 * 256;
        R = 12288; C = 256;
    } else {
        so = (long)z * 192 * HW;
        dofs = (long)z * HW * 192;
        R = 192; C = HW;
    }
    int r0 = blockIdx.y * 64, c0 = blockIdx.x * 64;
#pragma unroll
    for (int rr = 0; rr < 2; ++rr) {
        int r = rr * 32 + (tid >> 3);
        int cs = (tid & 7) * 8;
        *(bf16x8*)&T[r][cs] = *(const bf16x8*)(src + so + (long)(r0 + r) * C + c0 + cs);
    }
    __syncthreads();
#pragma unroll
    for (int cc = 0; cc < 2; ++cc) {
        int c = cc * 32 + (tid >> 3);
        int rs = (tid & 7) * 8;
        bf16x8 v;
#pragma unroll
        for (int e = 0; e < 8; ++e) v[e] = (short)T[rs + e][c];
        *(bf16x8*)(dst + dofs + (long)(c0 + c) * R + r0 + rs) = v;
    }
}

// ---------------- attn wide-j: Sp[sk][bh][i][j], block = 128 i x 256 j, 512 thr (8 waves).
// Q read once, K twice across the grid (was 2x/2x). grid (2, 1, 128).
__global__ __launch_bounds__(512, 4) void attn_qk(const unsigned short* __restrict__ qkT, float* __restrict__ Sp)
{
    __shared__ unsigned short Qs[128 * 40];
    __shared__ unsigned short Ks[256 * 40];
    int tid = threadIdx.x;
    int z = blockIdx.z; int bh = z >> 4, sk = z & 15; int b = bh >> 2, h = bh & 3;
    const unsigned short* qT = qkT + (long)(b * 8 + h) * 3145728;
    const unsigned short* kT = qkT + (long)(b * 8 + 4 + h) * 3145728;
    int i0 = blockIdx.x * 128;
    int w = tid >> 6, lane = tid & 63, lg = lane >> 4, li = lane & 15;
    int wm = w >> 2, wn = w & 3;
    int rq = tid >> 2, seg = (tid & 3) * 8;   // stage: Q[rq], K[rq], K[128+rq] col seg

    const unsigned short* qp  = qT + (long)(i0 + rq) * 12288 + sk * 768 + seg;
    const unsigned short* kp1 = kT + (long)rq * 12288 + sk * 768 + seg;
    const unsigned short* kp2 = kT + (long)(128 + rq) * 12288 + sk * 768 + seg;

    f32x4 acc[4][4];
#pragma unroll
    for (int i = 0; i < 4; ++i)
#pragma unroll
        for (int j = 0; j < 4; ++j) acc[i][j] = (f32x4){0.f, 0.f, 0.f, 0.f};

    bf16x8 qr = *(const bf16x8*)qp;
    bf16x8 kr1 = *(const bf16x8*)kp1;
    bf16x8 kr2 = *(const bf16x8*)kp2;

#pragma unroll 1
    for (int ks = 0; ks < 24; ++ks) {
        *(bf16x8*)&Qs[rq * 40 + seg] = qr;
        *(bf16x8*)&Ks[rq * 40 + seg] = kr1;
        *(bf16x8*)&Ks[(128 + rq) * 40 + seg] = kr2;
        if (ks < 23) {
            long o = (long)(ks + 1) * 32;
            qr  = *(const bf16x8*)(qp + o);
            kr1 = *(const bf16x8*)(kp1 + o);
            kr2 = *(const bf16x8*)(kp2 + o);
        }
        __syncthreads();
        bf16x8 af[4], bfr[4];
#pragma unroll
        for (int fa = 0; fa < 4; ++fa)
            af[fa] = *(const bf16x8*)&Qs[(wm * 64 + fa * 16 + li) * 40 + lg * 8];
#pragma unroll
        for (int fb = 0; fb < 4; ++fb)
            bfr[fb] = *(const bf16x8*)&Ks[(wn * 64 + fb * 16 + li) * 40 + lg * 8];
#pragma unroll
        for (int fa = 0; fa < 4; ++fa)
#pragma unroll
            for (int fb = 0; fb < 4; ++fb)
                acc[fa][fb] = __builtin_amdgcn_mfma_f32_16x16x32_bf16(af[fa], bfr[fb], acc[fa][fb], 0, 0, 0);
        __syncthreads();
    }

    float* op = Sp + ((long)(sk * 8 + bh) << 16);
#pragma unroll
    for (int fa = 0; fa < 4; ++fa) {
        int i = i0 + wm * 64 + fa * 16 + lg * 4;
#pragma unroll
        for (int fb = 0; fb < 4; ++fb) {
            int j = wn * 64 + fb * 16 + li;
#pragma unroll
            for (int ii = 0; ii < 4; ++ii)
                op[(long)(i + ii) * 256 + j] = acc[fa][fb][ii];
        }
    }
}

// ---------------- softmax over i with scaling; writes Pt in vattn B-fragment layout.
__global__ __launch_bounds__(256) void softmax_k(const float* __restrict__ Sp, const float* __restrict__ norms,
                                                 const float* __restrict__ temp, unsigned short* __restrict__ Pt)
{
    __shared__ float Sd[256 * 9];
    __shared__ float red[32 * 9];
    int tid = threadIdx.x;
    int g = blockIdx.x; int bh = g >> 5, jq = g & 31; int b = bh >> 2, h = bh & 3;
    int jl = tid & 7, iq = tid >> 3;
    int j = jq * 8 + jl;
    const float* nq = norms + (b * 8 + h) * 256;
    float invkj = norms[(b * 8 + 4 + h) * 256 + j] * temp[h];
    const float* sp = Sp + (long)bh * HW + j;

    float m = -1e30f;
#pragma unroll
    for (int ii = 0; ii < 8; ++ii) {
        int i = iq * 8 + ii;
        float s = 0.f;
#pragma unroll
        for (int sk = 0; sk < 16; ++sk) s += sp[((long)(sk * 8) << 16) + i * 256];
        float v = s * nq[i] * invkj;
        Sd[i * 9 + jl] = v;
        m = fmaxf(m, v);
    }
    red[iq * 9 + jl] = m;
    __syncthreads();
    m = -1e30f;
#pragma unroll
    for (int s2 = 0; s2 < 32; ++s2) m = fmaxf(m, red[s2 * 9 + jl]);
    __syncthreads();
    float sum = 0.f;
#pragma unroll
    for (int ii = 0; ii < 8; ++ii) sum += __expf(Sd[(iq * 8 + ii) * 9 + jl] - m);
    red[iq * 9 + jl] = sum;
    __syncthreads();
    sum = 0.f;
#pragma unroll
    for (int s2 = 0; s2 < 32; ++s2) sum += red[s2 * 9 + jl];
    float rs = 1.0f / sum;

    int fb = jq >> 1, li2 = (jq & 1) * 8 + jl;
    int ks = iq >> 2, lg = iq & 3;
    unsigned short* pt = Pt + (long)bh * HW + (long)((fb * 8 + ks) * 64 + lg * 16 + li2) * 8;
    bf16x8 pv;
#pragma unroll
    for (int ii = 0; ii < 8; ++ii)
        pv[ii] = (short)f2b(__expf(Sd[(iq * 8 + ii) * 9 + jl] - m) * rs);
    *(bf16x8*)pt = pv;
}

// ---------------- vattn: P in fragment layout (coalesced 1KB loads), no LDS. grid (192, 8)
__global__ __launch_bounds__(256) void vattn(const unsigned short* __restrict__ vpl,
                                             const unsigned short* __restrict__ Pt,
                                             unsigned short* __restrict__ vout)
{
    int tid = threadIdx.x;
    int w = tid >> 6, lane = tid & 63, lg = lane >> 4, li = lane & 15;
    int wm = w >> 1, wn = w & 1;
    int m0 = blockIdx.x * 64 + wm * 32;
    int bh = blockIdx.y; int b = bh >> 2, h = bh & 3;
    const unsigned short* V = vpl + (long)(b * 192 + h * 48) * HW;
    const unsigned short* P = Pt + (long)bh * HW + wn * 32768 + lane * 8;

    f32x4 acc[2][8];
#pragma unroll
    for (int i = 0; i < 2; ++i)
#pragma unroll
        for (int j = 0; j < 8; ++j) acc[i][j] = (f32x4){0.f, 0.f, 0.f, 0.f};

#pragma unroll 2
    for (int ks = 0; ks < 8; ++ks) {
        bf16x8 a0 = *(const bf16x8*)(V + (long)(m0 + li) * 256 + ks * 32 + lg * 8);
        bf16x8 a1 = *(const bf16x8*)(V + (long)(m0 + 16 + li) * 256 + ks * 32 + lg * 8);
#pragma unroll
        for (int fb2 = 0; fb2 < 8; ++fb2) {
            bf16x8 bb = *(const bf16x8*)(P + (fb2 * 8 + ks) * 512);
            acc[0][fb2] = __builtin_amdgcn_mfma_f32_16x16x32_bf16(a0, bb, acc[0][fb2], 0, 0, 0);
            acc[1][fb2] = __builtin_amdgcn_mfma_f32_16x16x32_bf16(a1, bb, acc[1][fb2], 0, 0, 0);
        }
    }
    unsigned short* ob = vout + (long)(b * 192 + h * 48) * HW;
#pragma unroll
    for (int fa = 0; fa < 2; ++fa) {
#pragma unroll
        for (int fb2 = 0; fb2 < 8; ++fb2) {
            int j = (wn * 8 + fb2) * 16 + li;
#pragma unroll
            for (int ii = 0; ii < 4; ++ii) {
                int m = m0 + fa * 16 + lg * 4 + ii;
                ob[((long)(m >> 8) << 16) + ((m & 255) << 8) + j] = f2b(acc[fa][fb2][ii]);
            }
        }
    }
}

extern "C" void kernel_launch(void* const* d_in, const int* in_sizes, int n_in,
                              void* d_out, int out_size, void* d_ws, size_t ws_size,
                              hipStream_t stream)
{
    (void)in_sizes; (void)n_in; (void)out_size; (void)ws_size;
    const float* x      = (const float*)d_in[0];
    const float* w_qkv  = (const float*)d_in[1];
    const float* w_dw   = (const float*)d_in[2];
    const float* w_proj = (const float*)d_in[3];
    const float* temp   = (const float*)d_in[4];
    float* out = (float*)d_out;
    char* ws = (char*)d_ws;

    unsigned short* qkv_pre = (unsigned short*)(ws + OFF_A0);
    unsigned short* vout    = (unsigned short*)(ws + OFF_A0);
    float*          Sp      = (float*)(ws + OFF_SP);
    unsigned short* voutT   = (unsigned short*)(ws + OFF_VOUTT);
    unsigned short* xb      = (unsigned short*)(ws + OFF_XQK);
    unsigned short* qkT     = (unsigned short*)(ws + OFF_XQK);
    unsigned short* vpl     = (unsigned short*)(ws + OFF_VPL);
    unsigned short* Pt      = (unsigned short*)(ws + OFF_PT);
    float*          normp   = (float*)(ws + OFF_NORMP);
    float*          norms   = (float*)(ws + OFF_NORMS);
    unsigned short* wqb     = (unsigned short*)(ws + OFF_WQ);
    unsigned short* wpb     = (unsigned short*)(ws + OFF_WP);

    conv_w<<<64, 256, 0, stream>>>(w_qkv, w_proj, wqb, wpb);
    conv_x<<<dim3(1024, 2), 256, 0, stream>>>(x, xb);
    hipMemsetAsync(normp, 0, 16384, stream);
    gemm_pm2<<<1024, 256, 0, stream>>>(wqb, xb, qkv_pre, nullptr, 9);
    dwconv2<<<dim3(8, 1152), 256, 0, stream>>>(qkv_pre, w_dw, qkT, vpl, normp);
    norms_fin<<<16, 256, 0, stream>>>(normp, norms);
    attn_qk<<<dim3(2, 1, 128), 512, 0, stream>>>(qkT, Sp);
    softmax_k<<<256, 256, 0, stream>>>(Sp, norms, temp, Pt);
    vattn<<<dim3(192, 8), 256, 0, stream>>>(vpl, Pt, vout);
    transpose_bf16<<<dim3(1024, 3, 2), 256, 0, stream>>>(vout, voutT, 1);
    gemm_pm2<<<1024, 256, 0, stream>>>(wpb, voutT, nullptr, out, 3);
}

// Round 12
// 357.116 us; speedup vs baseline: 1.1396x; 1.1396x over previous
//
#include <hip/hip_runtime.h>
#include <math.h>

#define HW 65536

typedef float f32x4 __attribute__((ext_vector_type(4)));
typedef short bf16x8 __attribute__((ext_vector_type(8)));
typedef short bf16x4 __attribute__((ext_vector_type(4)));

// ---- ws layout (byte offsets) ----
static constexpr size_t OFF_A0     = 0;
static constexpr size_t OFF_SP     = 50331648;
static constexpr size_t OFF_VOUTT  = 100663296;
static constexpr size_t OFF_XQK    = 150994944;
static constexpr size_t OFF_VPL    = 251658240;
static constexpr size_t OFF_PT     = 301989888;  // 1,048,576 B
static constexpr size_t OFF_WQ     = 303054848;  // 221,184 B
static constexpr size_t OFF_WP     = 303276032;  // 73,728 B
static constexpr size_t OFF_NORMS  = 303349760;  // 16,384 B
static constexpr size_t OFF_NORMP  = 303366144;  // 6,291,456 B (16*48*8*256 f32)  end 309,657,600
// round-0 layout proved >= 313 MB of ws is available.

__device__ inline float b2f(unsigned short u) { union { unsigned u; float f; } v; v.u = ((unsigned)u) << 16; return v.f; }
__device__ inline unsigned short f2b(float f) {
    union { float f; unsigned u; } v; v.f = f;
    return (unsigned short)((v.u + 0x7fffu + ((v.u >> 16) & 1u)) >> 16);
}

// ---------------- convert weights to bf16
__global__ __launch_bounds__(256) void conv_w(const float* __restrict__ wq, const float* __restrict__ wp,
                                              unsigned short* __restrict__ wqb, unsigned short* __restrict__ wpb)
{
    int t = blockIdx.x * 256 + threadIdx.x;
    int stride = gridDim.x * 256;
    for (int i = t; i < 576 * 192; i += stride) wqb[i] = f2b(wq[i]);
    for (int i = t; i < 192 * 192; i += stride) wpb[i] = f2b(wp[i]);
}

// ---------------- x fp32 planar [b][192][HW] -> xb bf16 pixel-major [b*HW][192]
__global__ __launch_bounds__(256) void conv_x(const float* __restrict__ x, unsigned short* __restrict__ xb)
{
    __shared__ unsigned short T[64 * 200];   // [px 64][c 192 pad 200]
    int tid = threadIdx.x;
    int b = blockIdx.y;
    long p0 = (long)blockIdx.x * 64;
#pragma unroll
    for (int it = 0; it < 12; ++it) {
        int c = it * 16 + (tid >> 4);
        int px = (tid & 15) * 4;
        float4 v = *(const float4*)(x + ((long)b * 192 + c) * HW + p0 + px);
        T[(px + 0) * 200 + c] = f2b(v.x);
        T[(px + 1) * 200 + c] = f2b(v.y);
        T[(px + 2) * 200 + c] = f2b(v.z);
        T[(px + 3) * 200 + c] = f2b(v.w);
    }
    __syncthreads();
    int px = tid >> 2, q = tid & 3;
    unsigned short* ob = xb + ((long)b * HW + p0 + px) * 192 + q * 48;
#pragma unroll
    for (int e = 0; e < 6; ++e)
        *(bf16x8*)(ob + e * 8) = *(const bf16x8*)&T[px * 200 + q * 48 + e * 8];
}

// ---------------- MFMA GEMM v2 (proven fastest): 128-px tile, coalesced LDS staging,
// b128 fragment gather, loop over M-tiles.
__global__ __launch_bounds__(256) void gemm_pm2(const unsigned short* __restrict__ Aw,
                                                const unsigned short* __restrict__ Bp,
                                                unsigned short* __restrict__ outb,
                                                float* __restrict__ outf, int Mtiles)
{
    __shared__ unsigned short Bs[128 * 200];
    int tid = threadIdx.x;
    int w = tid >> 6, lane = tid & 63, lg = lane >> 4, li = lane & 15;
    int wm = w >> 1, wn = w & 1;
    long pflat = (long)blockIdx.x * 128;

#pragma unroll
    for (int it = 0; it < 12; ++it) {
        int f = it * 256 + tid;
        int row = f / 24, cs = (f % 24) * 8;
        *(bf16x8*)&Bs[row * 200 + cs] = *(const bf16x8*)(Bp + (pflat + row) * 192 + cs);
    }
    __syncthreads();

    bf16x8 Bf[4][6];
#pragma unroll
    for (int fb = 0; fb < 4; ++fb)
#pragma unroll
        for (int ks = 0; ks < 6; ++ks)
            Bf[fb][ks] = *(const bf16x8*)&Bs[(wn * 64 + fb * 16 + li) * 200 + ks * 32 + lg * 8];

    const int b = (int)(blockIdx.x >> 9);
    const int pxl = ((int)blockIdx.x & 511) * 128 + wn * 64;
    const int Mtot = Mtiles * 64;

    for (int mt = 0; mt < Mtiles; ++mt) {
        int oc0 = mt * 64;
        const unsigned short* ab = Aw + (long)(oc0 + wm * 32 + li) * 192 + lg * 8;
        f32x4 acc[2][4];
#pragma unroll
        for (int i = 0; i < 2; ++i)
#pragma unroll
            for (int j = 0; j < 4; ++j) acc[i][j] = (f32x4){0.f, 0.f, 0.f, 0.f};
#pragma unroll
        for (int ks = 0; ks < 6; ++ks) {
            bf16x8 a0 = *(const bf16x8*)(ab + ks * 32);
            bf16x8 a1 = *(const bf16x8*)(ab + 16 * 192 + ks * 32);
#pragma unroll
            for (int fb = 0; fb < 4; ++fb) {
                acc[0][fb] = __builtin_amdgcn_mfma_f32_16x16x32_bf16(a0, Bf[fb][ks], acc[0][fb], 0, 0, 0);
                acc[1][fb] = __builtin_amdgcn_mfma_f32_16x16x32_bf16(a1, Bf[fb][ks], acc[1][fb], 0, 0, 0);
            }
        }
#pragma unroll
        for (int fa = 0; fa < 2; ++fa) {
            int m = oc0 + wm * 32 + fa * 16 + lg * 4;
#pragma unroll
            for (int fb = 0; fb < 4; ++fb) {
                int px = pxl + fb * 16 + li;
                long base = ((long)b * Mtot + m) * HW + px;
#pragma unroll
                for (int ii = 0; ii < 4; ++ii) {
                    if (outf) outf[base + (long)ii * HW] = acc[fa][fb][ii];
                    else      outb[base + (long)ii * HW] = f2b(acc[fa][fb][ii]);
                }
            }
        }
    }
}

// ---------------- depthwise 3x3 SAME v4: v2 + fused q/k column sum-of-squares written
// as per-block partials (NO atomics). grid (8 ystrips, 1152 planes)
__global__ __launch_bounds__(256) void dwconv2(const unsigned short* __restrict__ in,
                                               const float* __restrict__ wdw,
                                               unsigned short* __restrict__ qkT,
                                               unsigned short* __restrict__ vpl,
                                               float* __restrict__ normp)
{
    __shared__ unsigned short Ls[34 * 272];
    int tid = threadIdx.x;
    int zp = blockIdx.y;
    int b = zp / 576, ch3 = zp % 576;
    int y0 = blockIdx.x * 32;
    const unsigned short* ip = in + (long)zp * HW;
    float w9[9];
#pragma unroll
    for (int t = 0; t < 9; ++t) w9[t] = wdw[ch3 * 9 + t];

    const bf16x8 z8 = (bf16x8){0, 0, 0, 0, 0, 0, 0, 0};
    if (tid < 34)               *(bf16x8*)&Ls[tid * 272] = z8;
    else if (tid < 68)          *(bf16x8*)&Ls[(tid - 34) * 272 + 264] = z8;
#pragma unroll
    for (int it = 0; it < 5; ++it) {
        int task = it * 256 + tid;
        if (task < 1088) {
            int r = task >> 5, seg = task & 31;
            int gy = y0 - 1 + r;
            bf16x8 v = z8;
            if (gy >= 0 && gy < 256) v = *(const bf16x8*)(ip + gy * 256 + seg * 8);
            *(bf16x8*)&Ls[r * 272 + 8 + seg * 8] = v;
        }
    }
    __syncthreads();

    int xg = tid & 63, yg = tid >> 6;
    int x0 = xg * 4;
    float acc[8][4];
#pragma unroll
    for (int yy = 0; yy < 8; ++yy)
#pragma unroll
        for (int xi = 0; xi < 4; ++xi) acc[yy][xi] = 0.f;

#pragma unroll
    for (int rr = 0; rr < 10; ++rr) {
        const unsigned short* lp = &Ls[(yg * 8 + rr) * 272 + 8 + x0];
        bf16x4 A  = *(const bf16x4*)(lp - 4);
        bf16x4 Bv = *(const bf16x4*)(lp);
        bf16x4 Cv = *(const bf16x4*)(lp + 4);
        float f[6] = { b2f((unsigned short)A[3]),  b2f((unsigned short)Bv[0]),
                       b2f((unsigned short)Bv[1]), b2f((unsigned short)Bv[2]),
                       b2f((unsigned short)Bv[3]), b2f((unsigned short)Cv[0]) };
#pragma unroll
        for (int dy = 0; dy < 3; ++dy) {
            int yy = rr - dy;
            if (yy >= 0 && yy < 8) {
#pragma unroll
                for (int dx = 0; dx < 3; ++dx)
#pragma unroll
                    for (int xi = 0; xi < 4; ++xi)
                        acc[yy][xi] = fmaf(w9[dy * 3 + dx], f[dx + xi], acc[yy][xi]);
            }
        }
    }

    if (ch3 < 384) {
        int isk = ch3 >= 192 ? 1 : 0;
        int chq = ch3 - isk * 192;
        int hh = chq / 48, cc = chq % 48;
        int z2 = b * 8 + isk * 4 + hh;
        long zbase = (long)z2 * 3145728L + (long)cc * 256 + y0 + yg * 8;
#pragma unroll
        for (int xi = 0; xi < 4; ++xi) {
            bf16x8 pv;
#pragma unroll
            for (int yy = 0; yy < 8; ++yy) pv[yy] = (short)f2b(acc[yy][xi]);
            *(bf16x8*)(qkT + zbase + (long)(x0 + xi) * 12288) = pv;
        }
        // fused column sum-of-squares -> per-block partial slot (no atomics)
        float s[4];
#pragma unroll
        for (int xi = 0; xi < 4; ++xi) {
            float t = 0.f;
#pragma unroll
            for (int yy = 0; yy < 8; ++yy) t = fmaf(acc[yy][xi], acc[yy][xi], t);
            s[xi] = t;
        }
        __syncthreads();
        float* colsq = (float*)Ls;   // [4][256] = 4 KB (Ls dead)
#pragma unroll
        for (int xi = 0; xi < 4; ++xi) colsq[yg * 256 + x0 + xi] = s[xi];
        __syncthreads();
        if (yg == 0) {
            float* slot = normp + (((long)z2 * 48 + cc) * 8 + blockIdx.x) * 256;
            f32x4 t4;
#pragma unroll
            for (int xi = 0; xi < 4; ++xi)
                t4[xi] = colsq[x0 + xi] + colsq[256 + x0 + xi] +
                         colsq[512 + x0 + xi] + colsq[768 + x0 + xi];
            *(f32x4*)(slot + x0) = t4;
        }
    } else {
        unsigned short* ob = vpl + (long)(b * 192 + ch3 - 384) * HW + (long)(y0 + yg * 8) * 256 + x0;
#pragma unroll
        for (int yy = 0; yy < 8; ++yy) {
            bf16x4 pv;
#pragma unroll
            for (int xi = 0; xi < 4; ++xi) pv[xi] = (short)f2b(acc[yy][xi]);
            *(bf16x4*)(ob + yy * 256) = pv;
        }
    }
}

// ---------------- finalize norms: reduce 384 partials per (z2,x), then rsqrt-clamp
__global__ __launch_bounds__(256) void norms_fin(const float* __restrict__ normp, float* __restrict__ norms)
{
    int x = threadIdx.x, g = blockIdx.x;   // g = z2 (0..15)
    const float* p = normp + (long)g * 384 * 256 + x;
    float s = 0.f;
    for (int q = 0; q < 384; ++q) s += p[q * 256];
    norms[g * 256 + x] = 1.0f / fmaxf(sqrtf(s), 1e-12f);
}

// ---------------- generic bf16 transpose (64x64 tiles), mode 1: vout planar -> voutT pixel-major
__global__ __launch_bounds__(256) void transpose_bf16(const unsigned short* __restrict__ src,
                                                      unsigned short* __restrict__ dst, int mode)
{
    __shared__ unsigned short T[64][72];
    int tid = threadIdx.x;
    int z = blockIdx.z;
    long so, dofs; int R, C;
    if (mode == 0) {
        int b = z >> 3, isk = (z >> 2) & 1, h = z & 3;
        so = ((long)(b * 576 + isk * 192 + h * 48)) * HW;
        dofs = (long)z * 12288 * 256;
        R = 12288; C = 256;
    } else {
        so = (long)z * 192 * HW;
        dofs = (long)z * HW * 192;
        R = 192; C = HW;
    }
    int r0 = blockIdx.y * 64, c0 = blockIdx.x * 64;
#pragma unroll
    for (int rr = 0; rr < 2; ++rr) {
        int r = rr * 32 + (tid >> 3);
        int cs = (tid & 7) * 8;
        *(bf16x8*)&T[r][cs] = *(const bf16x8*)(src + so + (long)(r0 + r) * C + c0 + cs);
    }
    __syncthreads();
#pragma unroll
    for (int cc = 0; cc < 2; ++cc) {
        int c = cc * 32 + (tid >> 3);
        int rs = (tid & 7) * 8;
        bf16x8 v;
#pragma unroll
        for (int e = 0; e < 8; ++e) v[e] = (short)T[rs + e][c];
        *(bf16x8*)(dst + dofs + (long)(c0 + c) * R + r0 + rs) = v;
    }
}

// ---------------- attn wide-j: Sp[sk][bh][i][j], block = 128 i x 256 j, 512 thr (8 waves).
__global__ __launch_bounds__(512, 4) void attn_qk(const unsigned short* __restrict__ qkT, float* __restrict__ Sp)
{
    __shared__ unsigned short Qs[128 * 40];
    __shared__ unsigned short Ks[256 * 40];
    int tid = threadIdx.x;
    int z = blockIdx.z; int bh = z >> 4, sk = z & 15; int b = bh >> 2, h = bh & 3;
    const unsigned short* qT = qkT + (long)(b * 8 + h) * 3145728;
    const unsigned short* kT = qkT + (long)(b * 8 + 4 + h) * 3145728;
    int i0 = blockIdx.x * 128;
    int w = tid >> 6, lane = tid & 63, lg = lane >> 4, li = lane & 15;
    int wm = w >> 2, wn = w & 3;
    int rq = tid >> 2, seg = (tid & 3) * 8;

    const unsigned short* qp  = qT + (long)(i0 + rq) * 12288 + sk * 768 + seg;
    const unsigned short* kp1 = kT + (long)rq * 12288 + sk * 768 + seg;
    const unsigned short* kp2 = kT + (long)(128 + rq) * 12288 + sk * 768 + seg;

    f32x4 acc[4][4];
#pragma unroll
    for (int i = 0; i < 4; ++i)
#pragma unroll
        for (int j = 0; j < 4; ++j) acc[i][j] = (f32x4){0.f, 0.f, 0.f, 0.f};

    bf16x8 qr = *(const bf16x8*)qp;
    bf16x8 kr1 = *(const bf16x8*)kp1;
    bf16x8 kr2 = *(const bf16x8*)kp2;

#pragma unroll 1
    for (int ks = 0; ks < 24; ++ks) {
        *(bf16x8*)&Qs[rq * 40 + seg] = qr;
        *(bf16x8*)&Ks[rq * 40 + seg] = kr1;
        *(bf16x8*)&Ks[(128 + rq) * 40 + seg] = kr2;
        if (ks < 23) {
            long o = (long)(ks + 1) * 32;
            qr  = *(const bf16x8*)(qp + o);
            kr1 = *(const bf16x8*)(kp1 + o);
            kr2 = *(const bf16x8*)(kp2 + o);
        }
        __syncthreads();
        bf16x8 af[4], bfr[4];
#pragma unroll
        for (int fa = 0; fa < 4; ++fa)
            af[fa] = *(const bf16x8*)&Qs[(wm * 64 + fa * 16 + li) * 40 + lg * 8];
#pragma unroll
        for (int fb = 0; fb < 4; ++fb)
            bfr[fb] = *(const bf16x8*)&Ks[(wn * 64 + fb * 16 + li) * 40 + lg * 8];
#pragma unroll
        for (int fa = 0; fa < 4; ++fa)
#pragma unroll
            for (int fb = 0; fb < 4; ++fb)
                acc[fa][fb] = __builtin_amdgcn_mfma_f32_16x16x32_bf16(af[fa], bfr[fb], acc[fa][fb], 0, 0, 0);
        __syncthreads();
    }

    float* op = Sp + ((long)(sk * 8 + bh) << 16);
#pragma unroll
    for (int fa = 0; fa < 4; ++fa) {
        int i = i0 + wm * 64 + fa * 16 + lg * 4;
#pragma unroll
        for (int fb = 0; fb < 4; ++fb) {
            int j = wn * 64 + fb * 16 + li;
#pragma unroll
            for (int ii = 0; ii < 4; ++ii)
                op[(long)(i + ii) * 256 + j] = acc[fa][fb][ii];
        }
    }
}

// ---------------- softmax over i with scaling; writes Pt in vattn B-fragment layout.
__global__ __launch_bounds__(256) void softmax_k(const float* __restrict__ Sp, const float* __restrict__ norms,
                                                 const float* __restrict__ temp, unsigned short* __restrict__ Pt)
{
    __shared__ float Sd[256 * 9];
    __shared__ float red[32 * 9];
    int tid = threadIdx.x;
    int g = blockIdx.x; int bh = g >> 5, jq = g & 31; int b = bh >> 2, h = bh & 3;
    int jl = tid & 7, iq = tid >> 3;
    int j = jq * 8 + jl;
    const float* nq = norms + (b * 8 + h) * 256;
    float invkj = norms[(b * 8 + 4 + h) * 256 + j] * temp[h];
    const float* sp = Sp + (long)bh * HW + j;

    float m = -1e30f;
#pragma unroll
    for (int ii = 0; ii < 8; ++ii) {
        int i = iq * 8 + ii;
        float s = 0.f;
#pragma unroll
        for (int sk = 0; sk < 16; ++sk) s += sp[((long)(sk * 8) << 16) + i * 256];
        float v = s * nq[i] * invkj;
        Sd[i * 9 + jl] = v;
        m = fmaxf(m, v);
    }
    red[iq * 9 + jl] = m;
    __syncthreads();
    m = -1e30f;
#pragma unroll
    for (int s2 = 0; s2 < 32; ++s2) m = fmaxf(m, red[s2 * 9 + jl]);
    __syncthreads();
    float sum = 0.f;
#pragma unroll
    for (int ii = 0; ii < 8; ++ii) sum += __expf(Sd[(iq * 8 + ii) * 9 + jl] - m);
    red[iq * 9 + jl] = sum;
    __syncthreads();
    sum = 0.f;
#pragma unroll
    for (int s2 = 0; s2 < 32; ++s2) sum += red[s2 * 9 + jl];
    float rs = 1.0f / sum;

    int fb = jq >> 1, li2 = (jq & 1) * 8 + jl;
    int ks = iq >> 2, lg = iq & 3;
    unsigned short* pt = Pt + (long)bh * HW + (long)((fb * 8 + ks) * 64 + lg * 16 + li2) * 8;
    bf16x8 pv;
#pragma unroll
    for (int ii = 0; ii < 8; ++ii)
        pv[ii] = (short)f2b(__expf(Sd[(iq * 8 + ii) * 9 + jl] - m) * rs);
    *(bf16x8*)pt = pv;
}

// ---------------- vattn: P in fragment layout (coalesced 1KB loads), no LDS. grid (192, 8)
__global__ __launch_bounds__(256) void vattn(const unsigned short* __restrict__ vpl,
                                             const unsigned short* __restrict__ Pt,
                                             unsigned short* __restrict__ vout)
{
    int tid = threadIdx.x;
    int w = tid >> 6, lane = tid & 63, lg = lane >> 4, li = lane & 15;
    int wm = w >> 1, wn = w & 1;
    int m0 = blockIdx.x * 64 + wm * 32;
    int bh = blockIdx.y; int b = bh >> 2, h = bh & 3;
    const unsigned short* V = vpl + (long)(b * 192 + h * 48) * HW;
    const unsigned short* P = Pt + (long)bh * HW + wn * 32768 + lane * 8;

    f32x4 acc[2][8];
#pragma unroll
    for (int i = 0; i < 2; ++i)
#pragma unroll
        for (int j = 0; j < 8; ++j) acc[i][j] = (f32x4){0.f, 0.f, 0.f, 0.f};

#pragma unroll 2
    for (int ks = 0; ks < 8; ++ks) {
        bf16x8 a0 = *(const bf16x8*)(V + (long)(m0 + li) * 256 + ks * 32 + lg * 8);
        bf16x8 a1 = *(const bf16x8*)(V + (long)(m0 + 16 + li) * 256 + ks * 32 + lg * 8);
#pragma unroll
        for (int fb2 = 0; fb2 < 8; ++fb2) {
            bf16x8 bb = *(const bf16x8*)(P + (fb2 * 8 + ks) * 512);
            acc[0][fb2] = __builtin_amdgcn_mfma_f32_16x16x32_bf16(a0, bb, acc[0][fb2], 0, 0, 0);
            acc[1][fb2] = __builtin_amdgcn_mfma_f32_16x16x32_bf16(a1, bb, acc[1][fb2], 0, 0, 0);
        }
    }
    unsigned short* ob = vout + (long)(b * 192 + h * 48) * HW;
#pragma unroll
    for (int fa = 0; fa < 2; ++fa) {
#pragma unroll
        for (int fb2 = 0; fb2 < 8; ++fb2) {
            int j = (wn * 8 + fb2) * 16 + li;
#pragma unroll
            for (int ii = 0; ii < 4; ++ii) {
                int m = m0 + fa * 16 + lg * 4 + ii;
                ob[((long)(m >> 8) << 16) + ((m & 255) << 8) + j] = f2b(acc[fa][fb2][ii]);
            }
        }
    }
}

extern "C" void kernel_launch(void* const* d_in, const int* in_sizes, int n_in,
                              void* d_out, int out_size, void* d_ws, size_t ws_size,
                              hipStream_t stream)
{
    (void)in_sizes; (void)n_in; (void)out_size; (void)ws_size;
    const float* x      = (const float*)d_in[0];
    const float* w_qkv  = (const float*)d_in[1];
    const float* w_dw   = (const float*)d_in[2];
    const float* w_proj = (const float*)d_in[3];
    const float* temp   = (const float*)d_in[4];
    float* out = (float*)d_out;
    char* ws = (char*)d_ws;

    unsigned short* qkv_pre = (unsigned short*)(ws + OFF_A0);
    unsigned short* vout    = (unsigned short*)(ws + OFF_A0);
    float*          Sp      = (float*)(ws + OFF_SP);
    unsigned short* voutT   = (unsigned short*)(ws + OFF_VOUTT);
    unsigned short* xb      = (unsigned short*)(ws + OFF_XQK);
    unsigned short* qkT     = (unsigned short*)(ws + OFF_XQK);
    unsigned short* vpl     = (unsigned short*)(ws + OFF_VPL);
    unsigned short* Pt      = (unsigned short*)(ws + OFF_PT);
    float*          normp   = (float*)(ws + OFF_NORMP);
    float*          norms   = (float*)(ws + OFF_NORMS);
    unsigned short* wqb     = (unsigned short*)(ws + OFF_WQ);
    unsigned short* wpb     = (unsigned short*)(ws + OFF_WP);

    conv_w<<<64, 256, 0, stream>>>(w_qkv, w_proj, wqb, wpb);
    conv_x<<<dim3(1024, 2), 256, 0, stream>>>(x, xb);
    gemm_pm2<<<1024, 256, 0, stream>>>(wqb, xb, qkv_pre, nullptr, 9);
    dwconv2<<<dim3(8, 1152), 256, 0, stream>>>(qkv_pre, w_dw, qkT, vpl, normp);
    norms_fin<<<16, 256, 0, stream>>>(normp, norms);
    attn_qk<<<dim3(2, 1, 128), 512, 0, stream>>>(qkT, Sp);
    softmax_k<<<256, 256, 0, stream>>>(Sp, norms, temp, Pt);
    vattn<<<dim3(192, 8), 256, 0, stream>>>(vpl, Pt, vout);
    transpose_bf16<<<dim3(1024, 3, 2), 256, 0, stream>>>(vout, voutT, 1);
    gemm_pm2<<<1024, 256, 0, stream>>>(wpb, voutT, nullptr, out, 3);
}

// Round 13
// 355.477 us; speedup vs baseline: 1.1448x; 1.0046x over previous
//
#include <hip/hip_runtime.h>
#include <math.h>

#define HW 65536

typedef float f32x4 __attribute__((ext_vector_type(4)));
typedef short bf16x8 __attribute__((ext_vector_type(8)));
typedef short bf16x4 __attribute__((ext_vector_type(4)));

// ---- ws layout (byte offsets) ----
// [0,151M): qkv_t tile-major (dead after dwconv2) -> {vout @0, Sp @50.3M, voutT @100.7M}
// [151M,251.7M): xb (dead after qkv gemm) -> qkT
// [251.7M,302M): vpl
static constexpr size_t OFF_A0    = 0;
static constexpr size_t OFF_SP    = 50331648;
static constexpr size_t OFF_VOUTT = 100663296;
static constexpr size_t OFF_XQK   = 150994944;
static constexpr size_t OFF_VPL   = 251658240;
static constexpr size_t OFF_PT    = 301989888;  // 1,048,576 B
static constexpr size_t OFF_NORMS = 303038464;  // 16,384 B
static constexpr size_t OFF_WQ    = 303054848;  // 221,184 B
static constexpr size_t OFF_WP    = 303276032;  // 73,728 B   (end 303,349,760)

__device__ inline float b2f(unsigned short u) { union { unsigned u; float f; } v; v.u = ((unsigned)u) << 16; return v.f; }
__device__ inline unsigned short f2b(float f) {
    union { float f; unsigned u; } v; v.f = f;
    return (unsigned short)((v.u + 0x7fffu + ((v.u >> 16) & 1u)) >> 16);
}

// ---------------- convert weights to bf16
__global__ __launch_bounds__(256) void conv_w(const float* __restrict__ wq, const float* __restrict__ wp,
                                              unsigned short* __restrict__ wqb, unsigned short* __restrict__ wpb)
{
    int t = blockIdx.x * 256 + threadIdx.x;
    int stride = gridDim.x * 256;
    for (int i = t; i < 576 * 192; i += stride) wqb[i] = f2b(wq[i]);
    for (int i = t; i < 192 * 192; i += stride) wpb[i] = f2b(wp[i]);
}

// ---------------- x fp32 planar [b][192][HW] -> xb bf16 pixel-major [b*HW][192]
__global__ __launch_bounds__(256) void conv_x(const float* __restrict__ x, unsigned short* __restrict__ xb)
{
    __shared__ unsigned short T[64 * 200];   // [px 64][c 192 pad 200]
    int tid = threadIdx.x;
    int b = blockIdx.y;
    long p0 = (long)blockIdx.x * 64;
#pragma unroll
    for (int it = 0; it < 12; ++it) {
        int c = it * 16 + (tid >> 4);
        int px = (tid & 15) * 4;
        float4 v = *(const float4*)(x + ((long)b * 192 + c) * HW + p0 + px);
        T[(px + 0) * 200 + c] = f2b(v.x);
        T[(px + 1) * 200 + c] = f2b(v.y);
        T[(px + 2) * 200 + c] = f2b(v.z);
        T[(px + 3) * 200 + c] = f2b(v.w);
    }
    __syncthreads();
    int px = tid >> 2, q = tid & 3;
    unsigned short* ob = xb + ((long)b * HW + p0 + px) * 192 + q * 48;
#pragma unroll
    for (int e = 0; e < 6; ++e)
        *(bf16x8*)(ob + e * 8) = *(const bf16x8*)&T[px * 200 + q * 48 + e * 8];
}

// ---------------- MFMA GEMM, TILE-MAJOR output: qkv_t[b][pxtile][ch 576][px 128].
// Each block writes one contiguous 147KB slab (DRAM page locality).
__global__ __launch_bounds__(256) void gemm_pm2t(const unsigned short* __restrict__ Aw,
                                                 const unsigned short* __restrict__ Bp,
                                                 unsigned short* __restrict__ outt)
{
    __shared__ unsigned short Bs[128 * 200];
    int tid = threadIdx.x;
    int w = tid >> 6, lane = tid & 63, lg = lane >> 4, li = lane & 15;
    int wm = w >> 1, wn = w & 1;
    long pflat = (long)blockIdx.x * 128;

#pragma unroll
    for (int it = 0; it < 12; ++it) {
        int f = it * 256 + tid;
        int row = f / 24, cs = (f % 24) * 8;
        *(bf16x8*)&Bs[row * 200 + cs] = *(const bf16x8*)(Bp + (pflat + row) * 192 + cs);
    }
    __syncthreads();

    bf16x8 Bf[4][6];
#pragma unroll
    for (int fb = 0; fb < 4; ++fb)
#pragma unroll
        for (int ks = 0; ks < 6; ++ks)
            Bf[fb][ks] = *(const bf16x8*)&Bs[(wn * 64 + fb * 16 + li) * 200 + ks * 32 + lg * 8];

    const int b = (int)(blockIdx.x >> 9);
    const int pxt = (int)blockIdx.x & 511;
    unsigned short* ob = outt + ((long)(b * 512 + pxt)) * 576 * 128;

    for (int mt = 0; mt < 9; ++mt) {
        int oc0 = mt * 64;
        const unsigned short* ab = Aw + (long)(oc0 + wm * 32 + li) * 192 + lg * 8;
        f32x4 acc[2][4];
#pragma unroll
        for (int i = 0; i < 2; ++i)
#pragma unroll
            for (int j = 0; j < 4; ++j) acc[i][j] = (f32x4){0.f, 0.f, 0.f, 0.f};
#pragma unroll
        for (int ks = 0; ks < 6; ++ks) {
            bf16x8 a0 = *(const bf16x8*)(ab + ks * 32);
            bf16x8 a1 = *(const bf16x8*)(ab + 16 * 192 + ks * 32);
#pragma unroll
            for (int fb = 0; fb < 4; ++fb) {
                acc[0][fb] = __builtin_amdgcn_mfma_f32_16x16x32_bf16(a0, Bf[fb][ks], acc[0][fb], 0, 0, 0);
                acc[1][fb] = __builtin_amdgcn_mfma_f32_16x16x32_bf16(a1, Bf[fb][ks], acc[1][fb], 0, 0, 0);
            }
        }
#pragma unroll
        for (int fa = 0; fa < 2; ++fa) {
            int m = oc0 + wm * 32 + fa * 16 + lg * 4;
#pragma unroll
            for (int fb = 0; fb < 4; ++fb) {
                int pxi = wn * 64 + fb * 16 + li;
#pragma unroll
                for (int ii = 0; ii < 4; ++ii)
                    ob[(long)(m + ii) * 128 + pxi] = f2b(acc[fa][fb][ii]);
            }
        }
    }
}

// ---------------- MFMA GEMM v2 (planar out, for proj): 128-px tile, coalesced LDS staging.
__global__ __launch_bounds__(256) void gemm_pm2(const unsigned short* __restrict__ Aw,
                                                const unsigned short* __restrict__ Bp,
                                                unsigned short* __restrict__ outb,
                                                float* __restrict__ outf, int Mtiles)
{
    __shared__ unsigned short Bs[128 * 200];
    int tid = threadIdx.x;
    int w = tid >> 6, lane = tid & 63, lg = lane >> 4, li = lane & 15;
    int wm = w >> 1, wn = w & 1;
    long pflat = (long)blockIdx.x * 128;

#pragma unroll
    for (int it = 0; it < 12; ++it) {
        int f = it * 256 + tid;
        int row = f / 24, cs = (f % 24) * 8;
        *(bf16x8*)&Bs[row * 200 + cs] = *(const bf16x8*)(Bp + (pflat + row) * 192 + cs);
    }
    __syncthreads();

    bf16x8 Bf[4][6];
#pragma unroll
    for (int fb = 0; fb < 4; ++fb)
#pragma unroll
        for (int ks = 0; ks < 6; ++ks)
            Bf[fb][ks] = *(const bf16x8*)&Bs[(wn * 64 + fb * 16 + li) * 200 + ks * 32 + lg * 8];

    const int b = (int)(blockIdx.x >> 9);
    const int pxl = ((int)blockIdx.x & 511) * 128 + wn * 64;
    const int Mtot = Mtiles * 64;

    for (int mt = 0; mt < Mtiles; ++mt) {
        int oc0 = mt * 64;
        const unsigned short* ab = Aw + (long)(oc0 + wm * 32 + li) * 192 + lg * 8;
        f32x4 acc[2][4];
#pragma unroll
        for (int i = 0; i < 2; ++i)
#pragma unroll
            for (int j = 0; j < 4; ++j) acc[i][j] = (f32x4){0.f, 0.f, 0.f, 0.f};
#pragma unroll
        for (int ks = 0; ks < 6; ++ks) {
            bf16x8 a0 = *(const bf16x8*)(ab + ks * 32);
            bf16x8 a1 = *(const bf16x8*)(ab + 16 * 192 + ks * 32);
#pragma unroll
            for (int fb = 0; fb < 4; ++fb) {
                acc[0][fb] = __builtin_amdgcn_mfma_f32_16x16x32_bf16(a0, Bf[fb][ks], acc[0][fb], 0, 0, 0);
                acc[1][fb] = __builtin_amdgcn_mfma_f32_16x16x32_bf16(a1, Bf[fb][ks], acc[1][fb], 0, 0, 0);
            }
        }
#pragma unroll
        for (int fa = 0; fa < 2; ++fa) {
            int m = oc0 + wm * 32 + fa * 16 + lg * 4;
#pragma unroll
            for (int fb = 0; fb < 4; ++fb) {
                int px = pxl + fb * 16 + li;
                long base = ((long)b * Mtot + m) * HW + px;
#pragma unroll
                for (int ii = 0; ii < 4; ++ii) {
                    if (outf) outf[base + (long)ii * HW] = acc[fa][fb][ii];
                    else      outb[base + (long)ii * HW] = f2b(acc[fa][fb][ii]);
                }
            }
        }
    }
}

// ---------------- depthwise 3x3 SAME v2t: input is TILE-MAJOR qkv_t[b][pxtile][576][128];
// q/k written directly in qkT layout, v planar. grid (8 ystrips, 1152 planes)
__global__ __launch_bounds__(256) void dwconv2(const unsigned short* __restrict__ in,
                                               const float* __restrict__ wdw,
                                               unsigned short* __restrict__ qkT,
                                               unsigned short* __restrict__ vpl)
{
    __shared__ unsigned short Ls[34 * 272];
    int tid = threadIdx.x;
    int zp = blockIdx.y;
    int b = zp / 576, ch3 = zp % 576;
    int y0 = blockIdx.x * 32;
    const unsigned short* ipb = in + (long)b * 512 * 576 * 128 + (long)ch3 * 128;
    float w9[9];
#pragma unroll
    for (int t = 0; t < 9; ++t) w9[t] = wdw[ch3 * 9 + t];

    const bf16x8 z8 = (bf16x8){0, 0, 0, 0, 0, 0, 0, 0};
    if (tid < 34)               *(bf16x8*)&Ls[tid * 272] = z8;
    else if (tid < 68)          *(bf16x8*)&Ls[(tid - 34) * 272 + 264] = z8;
#pragma unroll
    for (int it = 0; it < 5; ++it) {
        int task = it * 256 + tid;
        if (task < 1088) {
            int r = task >> 5, seg = task & 31;
            int gy = y0 - 1 + r;
            bf16x8 v = z8;
            if (gy >= 0 && gy < 256)
                v = *(const bf16x8*)(ipb + (long)(gy * 2 + (seg >> 4)) * 73728 + (seg & 15) * 8);
            *(bf16x8*)&Ls[r * 272 + 8 + seg * 8] = v;
        }
    }
    __syncthreads();

    int xg = tid & 63, yg = tid >> 6;
    int x0 = xg * 4;
    float acc[8][4];
#pragma unroll
    for (int yy = 0; yy < 8; ++yy)
#pragma unroll
        for (int xi = 0; xi < 4; ++xi) acc[yy][xi] = 0.f;

#pragma unroll
    for (int rr = 0; rr < 10; ++rr) {
        const unsigned short* lp = &Ls[(yg * 8 + rr) * 272 + 8 + x0];
        bf16x4 A  = *(const bf16x4*)(lp - 4);
        bf16x4 Bv = *(const bf16x4*)(lp);
        bf16x4 Cv = *(const bf16x4*)(lp + 4);
        float f[6] = { b2f((unsigned short)A[3]),  b2f((unsigned short)Bv[0]),
                       b2f((unsigned short)Bv[1]), b2f((unsigned short)Bv[2]),
                       b2f((unsigned short)Bv[3]), b2f((unsigned short)Cv[0]) };
#pragma unroll
        for (int dy = 0; dy < 3; ++dy) {
            int yy = rr - dy;
            if (yy >= 0 && yy < 8) {
#pragma unroll
                for (int dx = 0; dx < 3; ++dx)
#pragma unroll
                    for (int xi = 0; xi < 4; ++xi)
                        acc[yy][xi] = fmaf(w9[dy * 3 + dx], f[dx + xi], acc[yy][xi]);
            }
        }
    }

    if (ch3 < 384) {
        int isk = ch3 >= 192 ? 1 : 0;
        int chq = ch3 - isk * 192;
        int hh = chq / 48, cc = chq % 48;
        long zbase = (long)(b * 8 + isk * 4 + hh) * 3145728L + (long)cc * 256 + y0 + yg * 8;
#pragma unroll
        for (int xi = 0; xi < 4; ++xi) {
            bf16x8 pv;
#pragma unroll
            for (int yy = 0; yy < 8; ++yy) pv[yy] = (short)f2b(acc[yy][xi]);
            *(bf16x8*)(qkT + zbase + (long)(x0 + xi) * 12288) = pv;
        }
    } else {
        unsigned short* ob = vpl + (long)(b * 192 + ch3 - 384) * HW + (long)(y0 + yg * 8) * 256 + x0;
#pragma unroll
        for (int yy = 0; yy < 8; ++yy) {
            bf16x4 pv;
#pragma unroll
            for (int xi = 0; xi < 4; ++xi) pv[xi] = (short)f2b(acc[yy][xi]);
            *(bf16x4*)(ob + yy * 256) = pv;
        }
    }
}

// ---------------- column norms: 1/max(||row of qkT||,eps). grid (256, 16)
__global__ __launch_bounds__(256) void norms_k(const unsigned short* __restrict__ qkT, float* __restrict__ norms)
{
    int i = blockIdx.x, z = blockIdx.y;
    const unsigned short* p = qkT + ((long)z * 256 + i) * 12288 + threadIdx.x * 8;
    float s = 0.f;
#pragma unroll
    for (int it = 0; it < 6; ++it) {
        bf16x8 v = *(const bf16x8*)(p + it * 2048);
#pragma unroll
        for (int e = 0; e < 8; ++e) { float f = b2f((unsigned short)v[e]); s = fmaf(f, f, s); }
    }
    for (int off = 32; off > 0; off >>= 1) s += __shfl_down(s, off, 64);
    __shared__ float r4[4];
    if ((threadIdx.x & 63) == 0) r4[threadIdx.x >> 6] = s;
    __syncthreads();
    if (threadIdx.x == 0) {
        float t = r4[0] + r4[1] + r4[2] + r4[3];
        norms[z * 256 + i] = 1.0f / fmaxf(sqrtf(t), 1e-12f);
    }
}

// ---------------- generic bf16 transpose (64x64 tiles), mode 1: vout planar -> voutT pixel-major
__global__ __launch_bounds__(256) void transpose_bf16(const unsigned short* __restrict__ src,
                                                      unsigned short* __restrict__ dst, int mode)
{
    __shared__ unsigned short T[64][72];
    int tid = threadIdx.x;
    int z = blockIdx.z;
    long so, dofs; int R, C;
    if (mode == 0) {
        int b = z >> 3, isk = (z >> 2) & 1, h = z & 3;
        so = ((long)(b * 576 + isk * 192 + h * 48)) * HW;
        dofs = (long)z * 12288 * 256;
        R = 12288; C = 256;
    } else {
        so = (long)z * 192 * HW;
        dofs = (long)z * HW * 192;
        R = 192; C = HW;
    }
    int r0 = blockIdx.y * 64, c0 = blockIdx.x * 64;
#pragma unroll
    for (int rr = 0; rr < 2; ++rr) {
        int r = rr * 32 + (tid >> 3);
        int cs = (tid & 7) * 8;
        *(bf16x8*)&T[r][cs] = *(const bf16x8*)(src + so + (long)(r0 + r) * C + c0 + cs);
    }
    __syncthreads();
#pragma unroll
    for (int cc = 0; cc < 2; ++cc) {
        int c = cc * 32 + (tid >> 3);
        int rs = (tid & 7) * 8;
        bf16x8 v;
#pragma unroll
        for (int e = 0; e < 8; ++e) v[e] = (short)T[rs + e][c];
        *(bf16x8*)(dst + dofs + (long)(c0 + c) * R + r0 + rs) = v;
    }
}

// ---------------- attn: Sp[sk][bh][i][j] partial of Q^T K. grid (2,2,128), K-chunk 768.
__global__ __launch_bounds__(256) void attn_qk(const unsigned short* __restrict__ qkT, float* __restrict__ Sp)
{
    __shared__ unsigned short Qs[128 * 40];
    __shared__ unsigned short Ks[128 * 40];
    int tid = threadIdx.x;
    int z = blockIdx.z; int bh = z >> 4, sk = z & 15; int b = bh >> 2, h = bh & 3;
    const unsigned short* qT = qkT + (long)(b * 8 + h) * 3145728;
    const unsigned short* kT = qkT + (long)(b * 8 + 4 + h) * 3145728;
    int i0 = blockIdx.x * 128, j0 = blockIdx.y * 128;
    int w = tid >> 6, lane = tid & 63, lg = lane >> 4, li = lane & 15;
    int wm = w >> 1, wn = w & 1;
    int srow = tid >> 2, sseg = (tid & 3) * 8;
    long qoff = (long)(i0 + srow) * 12288 + sk * 768 + sseg;
    long koff = (long)(j0 + srow) * 12288 + sk * 768 + sseg;

    f32x4 acc[4][4];
#pragma unroll
    for (int i = 0; i < 4; ++i)
#pragma unroll
        for (int j = 0; j < 4; ++j) acc[i][j] = (f32x4){0.f, 0.f, 0.f, 0.f};

    bf16x8 qr0 = *(const bf16x8*)(qT + qoff);
    bf16x8 qr1 = *(const bf16x8*)(qT + qoff + (long)64 * 12288);
    bf16x8 kr0 = *(const bf16x8*)(kT + koff);
    bf16x8 kr1 = *(const bf16x8*)(kT + koff + (long)64 * 12288);

#pragma unroll 1
    for (int ks = 0; ks < 24; ++ks) {
        *(bf16x8*)&Qs[srow * 40 + sseg] = qr0;
        *(bf16x8*)&Qs[(64 + srow) * 40 + sseg] = qr1;
        *(bf16x8*)&Ks[srow * 40 + sseg] = kr0;
        *(bf16x8*)&Ks[(64 + srow) * 40 + sseg] = kr1;
        if (ks < 23) {
            long o = (long)(ks + 1) * 32;
            qr0 = *(const bf16x8*)(qT + qoff + o);
            qr1 = *(const bf16x8*)(qT + qoff + (long)64 * 12288 + o);
            kr0 = *(const bf16x8*)(kT + koff + o);
            kr1 = *(const bf16x8*)(kT + koff + (long)64 * 12288 + o);
        }
        __syncthreads();
        bf16x8 af[4], bfr[4];
#pragma unroll
        for (int fa = 0; fa < 4; ++fa)
            af[fa] = *(const bf16x8*)&Qs[(wm * 64 + fa * 16 + li) * 40 + lg * 8];
#pragma unroll
        for (int fb = 0; fb < 4; ++fb)
            bfr[fb] = *(const bf16x8*)&Ks[(wn * 64 + fb * 16 + li) * 40 + lg * 8];
#pragma unroll
        for (int fa = 0; fa < 4; ++fa)
#pragma unroll
            for (int fb = 0; fb < 4; ++fb)
                acc[fa][fb] = __builtin_amdgcn_mfma_f32_16x16x32_bf16(af[fa], bfr[fb], acc[fa][fb], 0, 0, 0);
        __syncthreads();
    }

    float* op = Sp + ((long)(sk * 8 + bh) << 16);
#pragma unroll
    for (int fa = 0; fa < 4; ++fa) {
        int i = i0 + wm * 64 + fa * 16 + lg * 4;
#pragma unroll
        for (int fb = 0; fb < 4; ++fb) {
            int j = j0 + wn * 64 + fb * 16 + li;
#pragma unroll
            for (int ii = 0; ii < 4; ++ii)
                op[(long)(i + ii) * 256 + j] = acc[fa][fb][ii];
        }
    }
}

// ---------------- softmax over i with scaling; writes Pt in vattn B-fragment layout.
__global__ __launch_bounds__(256) void softmax_k(const float* __restrict__ Sp, const float* __restrict__ norms,
                                                 const float* __restrict__ temp, unsigned short* __restrict__ Pt)
{
    __shared__ float Sd[256 * 9];
    __shared__ float red[32 * 9];
    int tid = threadIdx.x;
    int g = blockIdx.x; int bh = g >> 5, jq = g & 31; int b = bh >> 2, h = bh & 3;
    int jl = tid & 7, iq = tid >> 3;
    int j = jq * 8 + jl;
    const float* nq = norms + (b * 8 + h) * 256;
    float invkj = norms[(b * 8 + 4 + h) * 256 + j] * temp[h];
    const float* sp = Sp + (long)bh * HW + j;

    float m = -1e30f;
#pragma unroll
    for (int ii = 0; ii < 8; ++ii) {
        int i = iq * 8 + ii;
        float s = 0.f;
#pragma unroll
        for (int sk = 0; sk < 16; ++sk) s += sp[((long)(sk * 8) << 16) + i * 256];
        float v = s * nq[i] * invkj;
        Sd[i * 9 + jl] = v;
        m = fmaxf(m, v);
    }
    red[iq * 9 + jl] = m;
    __syncthreads();
    m = -1e30f;
#pragma unroll
    for (int s2 = 0; s2 < 32; ++s2) m = fmaxf(m, red[s2 * 9 + jl]);
    __syncthreads();
    float sum = 0.f;
#pragma unroll
    for (int ii = 0; ii < 8; ++ii) sum += __expf(Sd[(iq * 8 + ii) * 9 + jl] - m);
    red[iq * 9 + jl] = sum;
    __syncthreads();
    sum = 0.f;
#pragma unroll
    for (int s2 = 0; s2 < 32; ++s2) sum += red[s2 * 9 + jl];
    float rs = 1.0f / sum;

    int fb = jq >> 1, li2 = (jq & 1) * 8 + jl;
    int ks = iq >> 2, lg = iq & 3;
    unsigned short* pt = Pt + (long)bh * HW + (long)((fb * 8 + ks) * 64 + lg * 16 + li2) * 8;
    bf16x8 pv;
#pragma unroll
    for (int ii = 0; ii < 8; ++ii)
        pv[ii] = (short)f2b(__expf(Sd[(iq * 8 + ii) * 9 + jl] - m) * rs);
    *(bf16x8*)pt = pv;
}

// ---------------- vattn: P in fragment layout (coalesced 1KB loads), no LDS. grid (192, 8)
__global__ __launch_bounds__(256) void vattn(const unsigned short* __restrict__ vpl,
                                             const unsigned short* __restrict__ Pt,
                                             unsigned short* __restrict__ vout)
{
    int tid = threadIdx.x;
    int w = tid >> 6, lane = tid & 63, lg = lane >> 4, li = lane & 15;
    int wm = w >> 1, wn = w & 1;
    int m0 = blockIdx.x * 64 + wm * 32;
    int bh = blockIdx.y; int b = bh >> 2, h = bh & 3;
    const unsigned short* V = vpl + (long)(b * 192 + h * 48) * HW;
    const unsigned short* P = Pt + (long)bh * HW + wn * 32768 + lane * 8;

    f32x4 acc[2][8];
#pragma unroll
    for (int i = 0; i < 2; ++i)
#pragma unroll
        for (int j = 0; j < 8; ++j) acc[i][j] = (f32x4){0.f, 0.f, 0.f, 0.f};

#pragma unroll 2
    for (int ks = 0; ks < 8; ++ks) {
        bf16x8 a0 = *(const bf16x8*)(V + (long)(m0 + li) * 256 + ks * 32 + lg * 8);
        bf16x8 a1 = *(const bf16x8*)(V + (long)(m0 + 16 + li) * 256 + ks * 32 + lg * 8);
#pragma unroll
        for (int fb2 = 0; fb2 < 8; ++fb2) {
            bf16x8 bb = *(const bf16x8*)(P + (fb2 * 8 + ks) * 512);
            acc[0][fb2] = __builtin_amdgcn_mfma_f32_16x16x32_bf16(a0, bb, acc[0][fb2], 0, 0, 0);
            acc[1][fb2] = __builtin_amdgcn_mfma_f32_16x16x32_bf16(a1, bb, acc[1][fb2], 0, 0, 0);
        }
    }
    unsigned short* ob = vout + (long)(b * 192 + h * 48) * HW;
#pragma unroll
    for (int fa = 0; fa < 2; ++fa) {
#pragma unroll
        for (int fb2 = 0; fb2 < 8; ++fb2) {
            int j = (wn * 8 + fb2) * 16 + li;
#pragma unroll
            for (int ii = 0; ii < 4; ++ii) {
                int m = m0 + fa * 16 + lg * 4 + ii;
                ob[((long)(m >> 8) << 16) + ((m & 255) << 8) + j] = f2b(acc[fa][fb2][ii]);
            }
        }
    }
}

extern "C" void kernel_launch(void* const* d_in, const int* in_sizes, int n_in,
                              void* d_out, int out_size, void* d_ws, size_t ws_size,
                              hipStream_t stream)
{
    (void)in_sizes; (void)n_in; (void)out_size; (void)ws_size;
    const float* x      = (const float*)d_in[0];
    const float* w_qkv  = (const float*)d_in[1];
    const float* w_dw   = (const float*)d_in[2];
    const float* w_proj = (const float*)d_in[3];
    const float* temp   = (const float*)d_in[4];
    float* out = (float*)d_out;
    char* ws = (char*)d_ws;

    unsigned short* qkv_t  = (unsigned short*)(ws + OFF_A0);
    unsigned short* vout   = (unsigned short*)(ws + OFF_A0);
    float*          Sp     = (float*)(ws + OFF_SP);
    unsigned short* voutT  = (unsigned short*)(ws + OFF_VOUTT);
    unsigned short* xb     = (unsigned short*)(ws + OFF_XQK);
    unsigned short* qkT    = (unsigned short*)(ws + OFF_XQK);
    unsigned short* vpl    = (unsigned short*)(ws + OFF_VPL);
    unsigned short* Pt     = (unsigned short*)(ws + OFF_PT);
    float*          norms  = (float*)(ws + OFF_NORMS);
    unsigned short* wqb    = (unsigned short*)(ws + OFF_WQ);
    unsigned short* wpb    = (unsigned short*)(ws + OFF_WP);

    conv_w<<<64, 256, 0, stream>>>(w_qkv, w_proj, wqb, wpb);
    conv_x<<<dim3(1024, 2), 256, 0, stream>>>(x, xb);
    gemm_pm2t<<<1024, 256, 0, stream>>>(wqb, xb, qkv_t);
    dwconv2<<<dim3(8, 1152), 256, 0, stream>>>(qkv_t, w_dw, qkT, vpl);
    norms_k<<<dim3(256, 16), 256, 0, stream>>>(qkT, norms);
    attn_qk<<<dim3(2, 2, 128), 256, 0, stream>>>(qkT, Sp);
    softmax_k<<<256, 256, 0, stream>>>(Sp, norms, temp, Pt);
    vattn<<<dim3(192, 8), 256, 0, stream>>>(vpl, Pt, vout);
    transpose_bf16<<<dim3(1024, 3, 2), 256, 0, stream>>>(vout, voutT, 1);
    gemm_pm2<<<1024, 256, 0, stream>>>(wpb, voutT, nullptr, out, 3);
}